// Round 13
// baseline (135.309 us; speedup 1.0000x reference)
//
#include <hip/hip_runtime.h>

// Decoder block: B=16, T=2048, E=256, H=8 (identical heads), DK=32, FF=1024
#define BB 16
#define TT 2048
#define EE 256
#define DK 32
#define MM (BB*TT)      // 32768 tokens
#define FF 1024

typedef __bf16 bf16_t;
typedef __bf16 bf16x8 __attribute__((ext_vector_type(8)));
typedef __bf16 bf16x4 __attribute__((ext_vector_type(4)));
typedef float  f32x4  __attribute__((ext_vector_type(4)));

__device__ __forceinline__ f32x4 mfma16(bf16x8 a, bf16x8 b, f32x4 c){
  return __builtin_amdgcn_mfma_f32_16x16x32_bf16(a, b, c, 0, 0, 0);
}
__device__ __forceinline__ void gload_lds16(const void* g, void* l){
  __builtin_amdgcn_global_load_lds((__attribute__((address_space(1))) void*)g,
                                   (__attribute__((address_space(3))) void*)l,
                                   16, 0, 0);
}

// ---------------------------------------------------------------------------
// prep: weight transposes/conversions.
// ---------------------------------------------------------------------------
__launch_bounds__(256)
__global__ void prep_kernel(const float* __restrict__ Wq, const float* __restrict__ Wk,
                            const float* __restrict__ Wv, const float* __restrict__ Wp,
                            const float* __restrict__ W1, const float* __restrict__ W2,
                            bf16_t* __restrict__ wqkv, float* __restrict__ wpe,
                            bf16_t* __restrict__ w1t, bf16_t* __restrict__ w2t)
{
  const int i = blockIdx.x*256 + threadIdx.x;
  if (i < 96*256) {
    const int r = i >> 8, c = i & 255;
    float v;
    if (r < 32)      v = Wq[c*32 + r] * 0.17677669529663687f;  // fold 1/sqrt(DK)
    else if (r < 64) v = Wk[c*32 + (r-32)];
    else             v = Wv[c*32 + (r-64)];
    wqkv[i] = (bf16_t)v;
  }
  if (i < 32*256) {
    const int d = i >> 8, n = i & 255;
    float s = 0.f;
    #pragma unroll
    for (int h = 0; h < 8; ++h) s += Wp[(h*32 + d)*256 + n];
    wpe[i] = s;
  }
  if (i < 1024*256) {
    const int n = i >> 8, k = i & 255;          // w1t[n][k] = W1[k][n]
    w1t[i] = (bf16_t)W1[(size_t)k*1024 + n];
  }
  if (i < 256*1024) {
    const int n = i >> 10, k = i & 1023;        // w2t[n][k] = W2[k][n]
    w2t[i] = (bf16_t)W2[(size_t)k*256 + n];
  }
}

// ---------------------------------------------------------------------------
// qkv: [MM,256] x [256,96] -> q [MM,32] (pre-scaled), k [MM,32], vT [B][32][T]
// ---------------------------------------------------------------------------
__launch_bounds__(256)
__global__ void qkv_kernel(const float* __restrict__ x, const bf16_t* __restrict__ wqkv,
                           bf16_t* __restrict__ q, bf16_t* __restrict__ kd,
                           bf16_t* __restrict__ vT)
{
  __shared__ bf16_t Ws[96*256];                 // rows of 512B, XOR-swizzled
  bf16_t* Vt = Ws;                              // 4 KB bounce tile, reused after barrier
  const int tid = threadIdx.x;
  #pragma unroll
  for (int i = 0; i < 12; ++i) {                // 3072 x 16B chunks
    const int v8  = tid + i*256;
    const int row = v8 >> 5;                    // 32 chunks per 512B row
    const int bir = (v8 & 31) * 16;
    *(bf16x8*)((char*)Ws + row*512 + (bir ^ ((row & 7) << 4))) =
        *(const bf16x8*)(wqkv + (size_t)v8*8);
  }
  __syncthreads();

  const int w = tid >> 6, l = tid & 63;
  const int lr = l & 15, lk4 = l >> 4, lkb = lk4*8;
  const int m0 = blockIdx.x * 64;
  const int arow = m0 + w*16 + lr;              // MFMA A row
  const float* xr = x + (size_t)arow * 256;

  f32x4 acc[6] = {};
  #pragma unroll
  for (int s = 0; s < 8; ++s) {
    const int kb = s*32 + lkb;
    const float4 v0 = *(const float4*)(xr + kb);
    const float4 v1 = *(const float4*)(xr + kb + 4);
    bf16x8 a;
    a[0]=(bf16_t)v0.x; a[1]=(bf16_t)v0.y; a[2]=(bf16_t)v0.z; a[3]=(bf16_t)v0.w;
    a[4]=(bf16_t)v1.x; a[5]=(bf16_t)v1.y; a[6]=(bf16_t)v1.z; a[7]=(bf16_t)v1.w;
    #pragma unroll
    for (int j = 0; j < 6; ++j) {
      const int nrow = j*16 + lr;
      const bf16x8 bf = *(const bf16x8*)((const char*)Ws + nrow*512 +
                                         ((kb*2) ^ ((nrow & 7) << 4)));
      acc[j] = mfma16(a, bf, acc[j]);
    }
  }
  // q, kd: direct (32-B row segments, small)
  #pragma unroll
  for (int j = 0; j < 4; ++j) {
    #pragma unroll
    for (int r = 0; r < 4; ++r) {
      const int orow = m0 + w*16 + lk4*4 + r;   // MFMA C row
      const int col  = j*16 + lr;
      const bf16_t v = (bf16_t)acc[j][r];
      if (col < 32) q[(size_t)orow*32 + col] = v;
      else          kd[(size_t)orow*32 + (col-32)] = v;
    }
  }
  __syncthreads();                              // all Ws reads done -> reuse as Vt
  // v-part -> Vt[32 d][64 t] with chunk-XOR swizzle
  #pragma unroll
  for (int j = 4; j < 6; ++j)
    #pragma unroll
    for (int r = 0; r < 4; ++r) {
      const int d = (j-4)*16 + lr;
      const int t = w*16 + lk4*4 + r;
      *(bf16_t*)((char*)Vt + d*128 + ((((t>>3) ^ (d&7))<<4) | ((t&7)*2))) =
          (bf16_t)acc[j][r];
    }
  __syncthreads();
  // coalesced vT store: 128-B row segments
  {
    const int d = tid >> 3, c8 = tid & 7;
    const bf16x8 v = *(const bf16x8*)((char*)Vt + d*128 + ((c8 ^ (d&7))<<4));
    *(bf16x8*)(vT + ((size_t)(m0 >> 11)*32 + d)*TT + (m0 & 2047) + c8*8) = v;
  }
}

// ---------------------------------------------------------------------------
// attnp: balanced split-KV causal flash attention, partials. (unchanged)
// ---------------------------------------------------------------------------
__launch_bounds__(256)
__global__ void attnp_kernel(const bf16_t* __restrict__ q, const bf16_t* __restrict__ kd,
                             const bf16_t* __restrict__ vT,
                             float* __restrict__ part_acc, float* __restrict__ part_ml)
{
  __shared__ bf16_t P[4][16*128];               // per-wave 4KB, 256B rows, swizzled
  const int tid = threadIdx.x;
  const int w = tid >> 6, l = tid & 63;
  const int wv = blockIdx.x*4 + w;              // 0..5119
  const int lr = l & 15, g4 = l >> 4;
  const float NEG_INF = -__builtin_inff();

  const int b = wv / 320;
  const int u = wv - b*320;
  int r, base;
  if      (u >= 192) { r = 3; base = 192; }
  else if (u >= 96)  { r = 2; base = 96;  }
  else if (u >= 32)  { r = 1; base = 32;  }
  else               { r = 0; base = 0;   }
  const int qq = u - base;
  const int g  = r*32 + qq / (r+1);             // query group
  const int c  = qq - (qq / (r+1))*(r+1);       // chunk index
  const int t_total = (g >> 3) + 1;             // 128-key tiles this group needs
  const int t0 = c*4;
  const int t1 = min(t0 + 4, t_total);

  const bf16_t* qb = q  + (size_t)b*TT*32;
  const bf16_t* kb = kd + (size_t)b*TT*32;
  const bf16_t* vb = vT + (size_t)b*32*TT;
  const int q0 = g*16;
  const int qg = q0 + lr;                       // this lane's query row

  const bf16x8 qa = *(const bf16x8*)(qb + (size_t)(q0 + lr)*32 + g4*8);
  const bf16_t* v0r = vb + (size_t)lr*TT;
  const bf16_t* v1r = vb + (size_t)(16 + lr)*TT;

  f32x4 acc0 = {0.f,0.f,0.f,0.f}, acc1 = {0.f,0.f,0.f,0.f};
  float mrun = NEG_INF, lsum = 0.f;
  char* pb = (char*)&P[w][0];
  const int swz = (lr & 7) << 4;
  const f32x4 zf = {0.f,0.f,0.f,0.f};

  for (int t = t0; t < t1; ++t) {
    const int k0 = t * 128;
    f32x4 s[8];
    #pragma unroll
    for (int cc = 0; cc < 8; ++cc) {
      const bf16x8 kf = *(const bf16x8*)(kb + (size_t)(k0 + cc*16 + lr)*32 + g4*8);
      s[cc] = mfma16(kf, qa, zf);               // D[key][query]; lane: key=cc*16+g4*4+r, q=lr
    }
    if (t == t_total - 1) {                     // diagonal tile: mask key > query
      #pragma unroll
      for (int cc = 0; cc < 8; ++cc)
        #pragma unroll
        for (int rr = 0; rr < 4; ++rr)
          if (k0 + cc*16 + g4*4 + rr > qg) s[cc][rr] = NEG_INF;
    }
    // in-lane softmax over 32 keys + cross-group combine (2 shfl)
    float mt = NEG_INF;
    #pragma unroll
    for (int cc = 0; cc < 8; ++cc) {
      float a01 = fmaxf(s[cc][0], s[cc][1]), a23 = fmaxf(s[cc][2], s[cc][3]);
      mt = fmaxf(mt, fmaxf(a01, a23));
    }
    mt = fmaxf(mt, __shfl_xor(mt, 16));
    mt = fmaxf(mt, __shfl_xor(mt, 32));
    const float mn = fmaxf(mrun, mt);
    const float sc = __expf(mrun - mn);         // first tile: exp(-inf)=0
    float ps = 0.f;
    #pragma unroll
    for (int cc = 0; cc < 8; ++cc) {
      float p0 = __expf(s[cc][0]-mn), p1 = __expf(s[cc][1]-mn);
      float p2 = __expf(s[cc][2]-mn), p3 = __expf(s[cc][3]-mn);
      s[cc][0]=p0; s[cc][1]=p1; s[cc][2]=p2; s[cc][3]=p3;
      ps += (p0+p1) + (p2+p3);
    }
    ps += __shfl_xor(ps, 16);
    ps += __shfl_xor(ps, 32);
    lsum = lsum*sc + ps;
    mrun = mn;
    acc0 *= sc; acc1 *= sc;
    // P -> LDS: lane writes its 32 keys for query lr as 8 x b64
    #pragma unroll
    for (int cc = 0; cc < 8; ++cc) {
      bf16x4 pk;
      pk[0]=(bf16_t)s[cc][0]; pk[1]=(bf16_t)s[cc][1];
      pk[2]=(bf16_t)s[cc][2]; pk[3]=(bf16_t)s[cc][3];
      *(bf16x4*)(pb + lr*256 + ((cc*32 + g4*8) ^ swz)) = pk;
    }
    // PV: A = vT rows (d), B = P rows (q); acc[d=g4*4+r][q=lr]
    #pragma unroll
    for (int h = 0; h < 4; ++h) {
      const bf16x8 pbf = *(const bf16x8*)(pb + lr*256 + ((h*64 + g4*16) ^ swz));
      acc0 = mfma16(*(const bf16x8*)(v0r + k0 + h*32 + g4*8), pbf, acc0);
      acc1 = mfma16(*(const bf16x8*)(v1r + k0 + h*32 + g4*8), pbf, acc1);
    }
  }
  // store partial (register layout; combine reads the same layout)
  float* pa = part_acc + (size_t)wv*512;
  *(f32x4*)(pa + l*8)     = acc0;
  *(f32x4*)(pa + l*8 + 4) = acc1;
  if (l < 16) {
    part_ml[wv*32 + l]      = mrun;
    part_ml[wv*32 + 16 + l] = lsum;
  }
}

// ---------------------------------------------------------------------------
// attnc: combine <=4 partials per query group, normalize, write attn bf16.
// ---------------------------------------------------------------------------
__launch_bounds__(256)
__global__ void attnc_kernel(const float* __restrict__ part_acc,
                             const float* __restrict__ part_ml,
                             bf16_t* __restrict__ attn)
{
  const int tid = threadIdx.x;
  const int id = blockIdx.x*4 + (tid >> 6);     // 0..2047
  const int l = tid & 63, lr = l & 15, g4 = l >> 4;
  const int b = id >> 7, g = id & 127;
  const int r = g >> 5;
  const int base = (r == 0) ? 0 : (r == 1) ? 32 : (r == 2) ? 96 : 192;
  const int p0 = b*320 + base + (g - (r << 5))*(r + 1);
  const int nc = r + 1;
  const float NEG_INF = -__builtin_inff();

  float m0v=NEG_INF,m1v=NEG_INF,m2v=NEG_INF,m3v=NEG_INF;
  float l0v=0,l1v=0,l2v=0,l3v=0;
  f32x4 a00={0,0,0,0},a01={0,0,0,0},a10={0,0,0,0},a11={0,0,0,0};
  f32x4 a20={0,0,0,0},a21={0,0,0,0},a30={0,0,0,0},a31={0,0,0,0};
  {
    const float* pa = part_acc + (size_t)p0*512;
    a00 = *(const f32x4*)(pa + l*8); a01 = *(const f32x4*)(pa + l*8 + 4);
    m0v = part_ml[p0*32 + lr]; l0v = part_ml[p0*32 + 16 + lr];
  }
  if (nc > 1) {
    const float* pa = part_acc + (size_t)(p0+1)*512;
    a10 = *(const f32x4*)(pa + l*8); a11 = *(const f32x4*)(pa + l*8 + 4);
    m1v = part_ml[(p0+1)*32 + lr]; l1v = part_ml[(p0+1)*32 + 16 + lr];
  }
  if (nc > 2) {
    const float* pa = part_acc + (size_t)(p0+2)*512;
    a20 = *(const f32x4*)(pa + l*8); a21 = *(const f32x4*)(pa + l*8 + 4);
    m2v = part_ml[(p0+2)*32 + lr]; l2v = part_ml[(p0+2)*32 + 16 + lr];
  }
  if (nc > 3) {
    const float* pa = part_acc + (size_t)(p0+3)*512;
    a30 = *(const f32x4*)(pa + l*8); a31 = *(const f32x4*)(pa + l*8 + 4);
    m3v = part_ml[(p0+3)*32 + lr]; l3v = part_ml[(p0+3)*32 + 16 + lr];
  }
  const float M = fmaxf(fmaxf(m0v, m1v), fmaxf(m2v, m3v));
  const float w0 = __expf(m0v - M), w1 = __expf(m1v - M);
  const float w2 = __expf(m2v - M), w3 = __expf(m3v - M);
  const float L = l0v*w0 + l1v*w1 + l2v*w2 + l3v*w3;
  const float inv = 1.0f / L;
  f32x4 o0 = (a00*w0 + a10*w1 + a20*w2 + a30*w3) * inv;
  f32x4 o1 = (a01*w0 + a11*w1 + a21*w2 + a31*w3) * inv;

  bf16_t* ao = attn + ((size_t)b*TT + g*16 + lr)*32;
  bf16x4 ob0, ob1;
  ob0[0]=(bf16_t)o0[0]; ob0[1]=(bf16_t)o0[1]; ob0[2]=(bf16_t)o0[2]; ob0[3]=(bf16_t)o0[3];
  ob1[0]=(bf16_t)o1[0]; ob1[1]=(bf16_t)o1[1]; ob1[2]=(bf16_t)o1[2]; ob1[3]=(bf16_t)o1[3];
  *(bf16x4*)(ao + g4*4)      = ob0;
  *(bf16x4*)(ao + 16 + g4*4) = ob1;
}

// ---------------------------------------------------------------------------
// LN1: y1b = bf16(LayerNorm(x + attn @ Wp_eff + bp))
// ---------------------------------------------------------------------------
__launch_bounds__(256)
__global__ void ln1_kernel(const float* __restrict__ x, const bf16_t* __restrict__ attn,
                           const float* __restrict__ wpe, const float* __restrict__ bp,
                           const float* __restrict__ g1, const float* __restrict__ be1,
                           bf16_t* __restrict__ y1b)
{
  __shared__ float Wp_s[32*256];
  const int tid = threadIdx.x;
  for (int i = tid; i < 32*64; i += 256)
    ((float4*)Wp_s)[i] = ((const float4*)wpe)[i];
  __syncthreads();

  const int w = tid >> 6, l = tid & 63;
  const int n = l * 4;
  const float4 gv  = *(const float4*)(g1  + n);
  const float4 bev = *(const float4*)(be1 + n);
  const float4 bpv = *(const float4*)(bp  + n);

  #pragma unroll 1
  for (int it = 0; it < 8; ++it) {
    const int row = blockIdx.x*32 + it*4 + w;
    const bf16_t* ar = attn + (size_t)row*32;
    float a[32];
    #pragma unroll
    for (int i = 0; i < 4; ++i) {
      const bf16x8 t = *(const bf16x8*)(ar + i*8);
      #pragma unroll
      for (int j = 0; j < 8; ++j) a[i*8 + j] = (float)t[j];
    }
    float mh[4] = {bpv.x, bpv.y, bpv.z, bpv.w};
    #pragma unroll
    for (int d = 0; d < 32; ++d) {
      const float4 wv = *(const float4*)(Wp_s + d*256 + n);
      const float ad = a[d];
      mh[0] = fmaf(ad, wv.x, mh[0]); mh[1] = fmaf(ad, wv.y, mh[1]);
      mh[2] = fmaf(ad, wv.z, mh[2]); mh[3] = fmaf(ad, wv.w, mh[3]);
    }
    const float4 xv = *(const float4*)(x + (size_t)row*256 + n);
    const float t0 = xv.x + mh[0], t1 = xv.y + mh[1];
    const float t2 = xv.z + mh[2], t3 = xv.w + mh[3];
    float s1 = (t0+t1) + (t2+t3);
    float s2 = (t0*t0 + t1*t1) + (t2*t2 + t3*t3);
    #pragma unroll
    for (int m = 1; m < 64; m <<= 1) { s1 += __shfl_xor(s1, m); s2 += __shfl_xor(s2, m); }
    const float mean = s1 * (1.0f/256.0f);
    const float var  = s2 * (1.0f/256.0f) - mean*mean;
    const float rs   = rsqrtf(var + 1e-5f);
    float4 yv;
    yv.x = (t0-mean)*rs*gv.x + bev.x; yv.y = (t1-mean)*rs*gv.y + bev.y;
    yv.z = (t2-mean)*rs*gv.z + bev.z; yv.w = (t3-mean)*rs*gv.w + bev.w;
    bf16x4 yb; yb[0]=(bf16_t)yv.x; yb[1]=(bf16_t)yv.y; yb[2]=(bf16_t)yv.z; yb[3]=(bf16_t)yv.w;
    *(bf16x4*)(y1b + (size_t)row*256 + n) = yb;
  }
}

// ---------------------------------------------------------------------------
// mlp: out = LayerNorm(y1 + gelu(y1 @ W1 + b1) @ W2 + b2), fully fused.
// TWO BLOCKS PER CU: grid 512 (M=64/block), 256 threads (4 waves), 72 KB LDS
// -> 2 independent barrier domains per CU (cross-block latency hiding, m114).
// FF1 SWAPPED (mfma(W1,y1) -> lane owns 4 consecutive h-cols) => gelu writes
// h via 2x ds_write_b64. Chunk=32 h-cols, 32 iters, W1/W2 dbuf, h single buf.
// LDS: W1 2x16K @0 | W2 2x16K @32K | h 4K @64K | bias 4K @68K = 72 KB
// ---------------------------------------------------------------------------
__launch_bounds__(256, 2)
__global__ void mlp_kernel(const bf16_t* __restrict__ y1b, const bf16_t* __restrict__ w1t,
                           const float* __restrict__ b1, const bf16_t* __restrict__ w2t,
                           const float* __restrict__ b2, const float* __restrict__ g2,
                           const float* __restrict__ be2, float* __restrict__ out)
{
  __shared__ char SM[73728];
  const int tid = threadIdx.x;
  const int w = tid >> 6, l = tid & 63;
  const int lr = l & 15, g4 = l >> 4;
  const int m0 = blockIdx.x * 64;
  const int rw = w >> 1;                // 2 row groups of 32 rows
  const int cw = w & 1;                 // 2 col groups
  const int mb  = rw * 32;              // wave row base (FF1 & FF2)
  const int wn1 = cw * 16;              // FF1 h-col slice within 32-chunk
  const int wn2 = cw * 128;             // FF2 out-col slice

  // bias b1 -> LDS @68K (1024 f32; 4/thread)
  {
    const float4 bv = *(const float4*)(b1 + tid*4);
    *(float4*)(SM + 69632 + tid*16) = bv;
  }
  // FF1 y1-frags (B operand): wave's 32 rows x K=256 -> 16 bf16x8 (64 VGPR)
  bf16x8 aA[2][8];
  #pragma unroll
  for (int t = 0; t < 2; ++t)
    #pragma unroll
    for (int kk = 0; kk < 8; ++kk)
      aA[t][kk] = *(const bf16x8*)(y1b +
          (size_t)(m0 + mb + t*16 + lr)*256 + kk*32 + g4*8);
  asm volatile("s_waitcnt vmcnt(0) lgkmcnt(0)" ::: "memory");
  __builtin_amdgcn_sched_barrier(0);

  // W1 chunk c -> slot s: [32 n][256 k], 512B rows, chunk-XOR swizzle.
  // 4 gload_lds16 per thread (1024 units / 256 threads).
  #define ST_W1(c, s)                                                         \
    { _Pragma("unroll")                                                       \
      for (int p_ = 0; p_ < 4; ++p_) {                                        \
        const int idx_ = p_*256 + tid;                                        \
        const int r_ = idx_ >> 5, c_ = idx_ & 31;                             \
        const int sc_ = (c_ & 24) | ((c_ ^ r_) & 7);                          \
        gload_lds16(w1t + (size_t)((c)*32 + r_)*256 + sc_*8,                  \
                    SM + (s)*16384 + idx_*16);                                \
      } }
  // W2 chunk c -> slot s: [256 n2][32 k], 64B rows, (n&3)-XOR swizzle.
  #define ST_W2(c, s)                                                         \
    { _Pragma("unroll")                                                       \
      for (int p_ = 0; p_ < 4; ++p_) {                                        \
        const int idx_ = p_*256 + tid;                                        \
        const int r_ = idx_ >> 2, c_ = idx_ & 3;                              \
        gload_lds16(w2t + (size_t)r_*1024 + (c)*32 + ((c_ ^ r_) & 3)*8,       \
                    SM + 32768 + (s)*16384 + idx_*16);                        \
      } }

  ST_W1(0, 0);
  ST_W2(0, 0);

  f32x4 oacc[2][8] = {};
  char* hb = SM + 65536;                // h [64 m][32 n], 64B rows, swizzled

  #pragma unroll 1
  for (int i = 0; i < 32; ++i) {
    asm volatile("s_waitcnt vmcnt(0)" ::: "memory");      // W(i) landed
    __builtin_amdgcn_sched_barrier(0);
    __builtin_amdgcn_s_barrier();                         // B1: h(i-1) fully read
    __builtin_amdgcn_sched_barrier(0);

    // ---- FF1(i) swapped: D[n][m]; lane: n = wn1+g4*4+r, m = mb+t*16+lr
    const char* sw1 = SM + (i & 1)*16384;
    f32x4 ah[2] = {};
    __builtin_amdgcn_s_setprio(1);
    #pragma unroll
    for (int kk = 0; kk < 8; ++kk) {
      const int row = wn1 + lr;                           // W1 A-frag row (n)
      const bf16x8 wf = *(const bf16x8*)(sw1 + row*512 +
                                         ((kk*64 + g4*16) ^ ((row & 7) << 4)));
      ah[0] = mfma16(wf, aA[0][kk], ah[0]);
      ah[1] = mfma16(wf, aA[1][kk], ah[1]);
    }
    __builtin_amdgcn_s_setprio(0);
    // gelu -> h via b64 writes (4 consecutive n per lane)
    {
      const float4 bias = *(const float4*)(SM + 69632 + (i*32 + wn1 + g4*4)*4);
      #pragma unroll
      for (int t = 0; t < 2; ++t) {
        const int m = mb + t*16 + lr;
        bf16x4 hv;
        #pragma unroll
        for (int r = 0; r < 4; ++r) {
          const float v = ah[t][r] + bias[r];
          const float z = 1.5957691216057308f * v * fmaf(0.044715f, v*v, 1.0f);
          hv[r] = (bf16_t)(v * __builtin_amdgcn_rcpf(1.0f + __expf(-z)));
        }
        *(bf16x4*)(hb + m*64 + (((wn1 + g4*4)*2) ^ ((m & 3) << 4))) = hv;
      }
    }
    asm volatile("s_waitcnt lgkmcnt(0)" ::: "memory");    // h committed
    __builtin_amdgcn_sched_barrier(0);
    __builtin_amdgcn_s_barrier();                         // B2: h visible
    __builtin_amdgcn_sched_barrier(0);
    // ---- FF2(i): oacc[32 rows x 128 cols] += h x W2c  (K=32)
    const char* sw2 = SM + 32768 + (i & 1)*16384;
    __builtin_amdgcn_s_setprio(1);
    {
      bf16x8 ha[2], wb[8];
      #pragma unroll
      for (int i3 = 0; i3 < 2; ++i3) {
        const int row = mb + i3*16 + lr;
        ha[i3] = *(const bf16x8*)(hb + row*64 + ((g4*16) ^ ((row & 3) << 4)));
      }
      #pragma unroll
      for (int j3 = 0; j3 < 8; ++j3) {
        const int n = wn2 + j3*16 + lr;
        wb[j3] = *(const bf16x8*)(sw2 + n*64 + ((g4*16) ^ ((n & 3) << 4)));
      }
      #pragma unroll
      for (int i3 = 0; i3 < 2; ++i3)
        #pragma unroll
        for (int j3 = 0; j3 < 8; ++j3)
          oacc[i3][j3] = mfma16(ha[i3], wb[j3], oacc[i3][j3]);
    }
    __builtin_amdgcn_s_setprio(0);
    // ---- restage into slot (i+1)&1 (last read before B1 of this iter: safe)
    if (i < 31) { ST_W1(i+1, (i+1)&1); ST_W2(i+1, (i+1)&1); }
  }
  #undef ST_W1
  #undef ST_W2

  // ---- epilogue: + b2 + residual(y1b), row LayerNorm over 256 cols
  float b2r[8], g2r[8], be2r[8];
  #pragma unroll
  for (int j3 = 0; j3 < 8; ++j3) {
    const int col = wn2 + j3*16 + lr;
    b2r[j3] = b2[col]; g2r[j3] = g2[col]; be2r[j3] = be2[col];
  }
  #pragma unroll
  for (int i3 = 0; i3 < 2; ++i3)
    #pragma unroll
    for (int r = 0; r < 4; ++r) {
      const int grow = m0 + mb + i3*16 + g4*4 + r;
      #pragma unroll
      for (int j3 = 0; j3 < 8; ++j3) {
        const int col = wn2 + j3*16 + lr;
        oacc[i3][j3][r] += b2r[j3] + (float)y1b[(size_t)grow*256 + col];
      }
    }
  __syncthreads();                              // loop LDS done -> alias red
  float* red = (float*)SM;                      // [64][4] f32 = 1 KB
  #pragma unroll
  for (int i3 = 0; i3 < 2; ++i3)
    #pragma unroll
    for (int r = 0; r < 4; ++r) {
      float s1 = 0.f, s2 = 0.f;
      #pragma unroll
      for (int j3 = 0; j3 < 8; ++j3) {
        s1 += oacc[i3][j3][r]; s2 += oacc[i3][j3][r]*oacc[i3][j3][r];
      }
      #pragma unroll
      for (int m = 1; m < 16; m <<= 1) { s1 += __shfl_xor(s1, m); s2 += __shfl_xor(s2, m); }
      if (lr == 0) {
        const int rl = mb + i3*16 + g4*4 + r;
        red[rl*4 + cw*2]     = s1;
        red[rl*4 + cw*2 + 1] = s2;
      }
    }
  __syncthreads();
  #pragma unroll
  for (int i3 = 0; i3 < 2; ++i3)
    #pragma unroll
    for (int r = 0; r < 4; ++r) {
      const int rl = mb + i3*16 + g4*4 + r;
      const float S1 = red[rl*4+0] + red[rl*4+2];
      const float S2 = red[rl*4+1] + red[rl*4+3];
      const float mean = S1 * (1.0f/256.0f);
      const float var  = S2 * (1.0f/256.0f) - mean*mean;
      const float rs   = rsqrtf(var + 1e-5f);
      #pragma unroll
      for (int j3 = 0; j3 < 8; ++j3) {
        const int col = wn2 + j3*16 + lr;
        out[(size_t)(m0 + rl)*256 + col] = (oacc[i3][j3][r] - mean)*rs*g2r[j3] + be2r[j3];
      }
    }
}

// ---------------------------------------------------------------------------
extern "C" void kernel_launch(void* const* d_in, const int* in_sizes, int n_in,
                              void* d_out, int out_size, void* d_ws, size_t ws_size,
                              hipStream_t stream)
{
  const float* x   = (const float*)d_in[0];
  const float* Wq  = (const float*)d_in[1];
  const float* Wk  = (const float*)d_in[2];
  const float* Wv  = (const float*)d_in[3];
  const float* Wp  = (const float*)d_in[4];
  const float* bp  = (const float*)d_in[5];
  const float* W1  = (const float*)d_in[6];
  const float* b1  = (const float*)d_in[7];
  const float* W2  = (const float*)d_in[8];
  const float* b2  = (const float*)d_in[9];
  const float* g1  = (const float*)d_in[10];
  const float* be1 = (const float*)d_in[11];
  const float* g2  = (const float*)d_in[12];
  const float* be2 = (const float*)d_in[13];

  char* ws = (char*)d_ws;
  bf16_t* qd   = (bf16_t*)(ws + ((size_t)0  << 20));  // 2 MB
  bf16_t* kd   = (bf16_t*)(ws + ((size_t)2  << 20));  // 2 MB
  bf16_t* vTd  = (bf16_t*)(ws + ((size_t)4  << 20));  // 2 MB
  bf16_t* attn = (bf16_t*)(ws + ((size_t)6  << 20));  // 2 MB
  bf16_t* y1b  = (bf16_t*)(ws + ((size_t)8  << 20));  // 16 MB
  bf16_t* wqkv = (bf16_t*)(ws + ((size_t)24 << 20));
  float*  wpe  = (float*) (ws + ((size_t)25 << 20));
  bf16_t* w1t  = (bf16_t*)(ws + ((size_t)26 << 20));  // 512 KB
  bf16_t* w2t  = (bf16_t*)(ws + ((size_t)27 << 20));  // 512 KB
  float*  pml  = (float*) (ws + ((size_t)28 << 20));  // 640 KB
  float*  pacc = (float*) (ws + ((size_t)29 << 20));  // 10 MB
  float* out = (float*)d_out;

  prep_kernel<<<1024, 256, 0, stream>>>(Wq, Wk, Wv, Wp, W1, W2, wqkv, wpe, w1t, w2t);
  qkv_kernel<<<512, 256, 0, stream>>>(x, wqkv, qd, kd, vTd);
  attnp_kernel<<<1280, 256, 0, stream>>>(qd, kd, vTd, pacc, pml);
  attnc_kernel<<<512, 256, 0, stream>>>(pacc, pml, attn);
  ln1_kernel<<<1024, 256, 0, stream>>>(x, attn, wpe, bp, g1, be1, y1b);
  mlp_kernel<<<512, 256, 0, stream>>>(y1b, w1t, b1, w2t, b2, g2, be2, out);
}

// Round 15
// 123.234 us; speedup vs baseline: 1.0980x; 1.0980x over previous
//
#include <hip/hip_runtime.h>

// Decoder block: B=16, T=2048, E=256, H=8 (identical heads), DK=32, FF=1024
#define BB 16
#define TT 2048
#define EE 256
#define DK 32
#define MM (BB*TT)      // 32768 tokens
#define FF 1024

typedef __bf16 bf16_t;
typedef __bf16 bf16x8 __attribute__((ext_vector_type(8)));
typedef __bf16 bf16x4 __attribute__((ext_vector_type(4)));
typedef float  f32x4  __attribute__((ext_vector_type(4)));

__device__ __forceinline__ f32x4 mfma16(bf16x8 a, bf16x8 b, f32x4 c){
  return __builtin_amdgcn_mfma_f32_16x16x32_bf16(a, b, c, 0, 0, 0);
}
__device__ __forceinline__ void gload_lds16(const void* g, void* l){
  __builtin_amdgcn_global_load_lds((__attribute__((address_space(1))) void*)g,
                                   (__attribute__((address_space(3))) void*)l,
                                   16, 0, 0);
}

// ---------------------------------------------------------------------------
// prep: weight transposes/conversions.
//   wqkv [96][256] bf16 ; wpT [256 n][32 k] bf16 = (sum_h Wp[h*32+k][n])^T
//   w1t [1024][256] bf16 = W1^T ; w2t [256][1024] bf16 = W2^T
// ---------------------------------------------------------------------------
__launch_bounds__(256)
__global__ void prep_kernel(const float* __restrict__ Wq, const float* __restrict__ Wk,
                            const float* __restrict__ Wv, const float* __restrict__ Wp,
                            const float* __restrict__ W1, const float* __restrict__ W2,
                            bf16_t* __restrict__ wqkv, bf16_t* __restrict__ wpT,
                            bf16_t* __restrict__ w1t, bf16_t* __restrict__ w2t)
{
  const int i = blockIdx.x*256 + threadIdx.x;
  if (i < 96*256) {
    const int r = i >> 8, c = i & 255;
    float v;
    if (r < 32)      v = Wq[c*32 + r] * 0.17677669529663687f;  // fold 1/sqrt(DK)
    else if (r < 64) v = Wk[c*32 + (r-32)];
    else             v = Wv[c*32 + (r-64)];
    wqkv[i] = (bf16_t)v;
  }
  if (i < 256*32) {
    const int n = i >> 5, k = i & 31;
    float s = 0.f;
    #pragma unroll
    for (int h = 0; h < 8; ++h) s += Wp[(h*32 + k)*256 + n];
    wpT[i] = (bf16_t)s;
  }
  if (i < 1024*256) {
    const int n = i >> 8, k = i & 255;          // w1t[n][k] = W1[k][n]
    w1t[i] = (bf16_t)W1[(size_t)k*1024 + n];
  }
  if (i < 256*1024) {
    const int n = i >> 10, k = i & 1023;        // w2t[n][k] = W2[k][n]
    w2t[i] = (bf16_t)W2[(size_t)k*256 + n];
  }
}

// ---------------------------------------------------------------------------
// qkv: [MM,256] x [256,96] -> q [MM,32] (pre-scaled), k [MM,32], vT [B][32][T]
// ---------------------------------------------------------------------------
__launch_bounds__(256)
__global__ void qkv_kernel(const float* __restrict__ x, const bf16_t* __restrict__ wqkv,
                           bf16_t* __restrict__ q, bf16_t* __restrict__ kd,
                           bf16_t* __restrict__ vT)
{
  __shared__ bf16_t Ws[96*256];                 // rows of 512B, XOR-swizzled
  bf16_t* Vt = Ws;                              // 4 KB bounce tile, reused after barrier
  const int tid = threadIdx.x;
  #pragma unroll
  for (int i = 0; i < 12; ++i) {                // 3072 x 16B chunks
    const int v8  = tid + i*256;
    const int row = v8 >> 5;                    // 32 chunks per 512B row
    const int bir = (v8 & 31) * 16;
    *(bf16x8*)((char*)Ws + row*512 + (bir ^ ((row & 7) << 4))) =
        *(const bf16x8*)(wqkv + (size_t)v8*8);
  }
  __syncthreads();

  const int w = tid >> 6, l = tid & 63;
  const int lr = l & 15, lk4 = l >> 4, lkb = lk4*8;
  const int m0 = blockIdx.x * 64;
  const int arow = m0 + w*16 + lr;              // MFMA A row
  const float* xr = x + (size_t)arow * 256;

  f32x4 acc[6] = {};
  #pragma unroll
  for (int s = 0; s < 8; ++s) {
    const int kb = s*32 + lkb;
    const float4 v0 = *(const float4*)(xr + kb);
    const float4 v1 = *(const float4*)(xr + kb + 4);
    bf16x8 a;
    a[0]=(bf16_t)v0.x; a[1]=(bf16_t)v0.y; a[2]=(bf16_t)v0.z; a[3]=(bf16_t)v0.w;
    a[4]=(bf16_t)v1.x; a[5]=(bf16_t)v1.y; a[6]=(bf16_t)v1.z; a[7]=(bf16_t)v1.w;
    #pragma unroll
    for (int j = 0; j < 6; ++j) {
      const int nrow = j*16 + lr;
      const bf16x8 bf = *(const bf16x8*)((const char*)Ws + nrow*512 +
                                         ((kb*2) ^ ((nrow & 7) << 4)));
      acc[j] = mfma16(a, bf, acc[j]);
    }
  }
  // q, kd: direct (32-B row segments, small)
  #pragma unroll
  for (int j = 0; j < 4; ++j) {
    #pragma unroll
    for (int r = 0; r < 4; ++r) {
      const int orow = m0 + w*16 + lk4*4 + r;   // MFMA C row
      const int col  = j*16 + lr;
      const bf16_t v = (bf16_t)acc[j][r];
      if (col < 32) q[(size_t)orow*32 + col] = v;
      else          kd[(size_t)orow*32 + (col-32)] = v;
    }
  }
  __syncthreads();                              // all Ws reads done -> reuse as Vt
  // v-part -> Vt[32 d][64 t] with chunk-XOR swizzle
  #pragma unroll
  for (int j = 4; j < 6; ++j)
    #pragma unroll
    for (int r = 0; r < 4; ++r) {
      const int d = (j-4)*16 + lr;
      const int t = w*16 + lk4*4 + r;
      *(bf16_t*)((char*)Vt + d*128 + ((((t>>3) ^ (d&7))<<4) | ((t&7)*2))) =
          (bf16_t)acc[j][r];
    }
  __syncthreads();
  // coalesced vT store: 128-B row segments
  {
    const int d = tid >> 3, c8 = tid & 7;
    const bf16x8 v = *(const bf16x8*)((char*)Vt + d*128 + ((c8 ^ (d&7))<<4));
    *(bf16x8*)(vT + ((size_t)(m0 >> 11)*32 + d)*TT + (m0 & 2047) + c8*8) = v;
  }
}

// ---------------------------------------------------------------------------
// attnp: balanced split-KV causal flash attention, partials. (unchanged)
// ---------------------------------------------------------------------------
__launch_bounds__(256)
__global__ void attnp_kernel(const bf16_t* __restrict__ q, const bf16_t* __restrict__ kd,
                             const bf16_t* __restrict__ vT,
                             float* __restrict__ part_acc, float* __restrict__ part_ml)
{
  __shared__ bf16_t P[4][16*128];               // per-wave 4KB, 256B rows, swizzled
  const int tid = threadIdx.x;
  const int w = tid >> 6, l = tid & 63;
  const int wv = blockIdx.x*4 + w;              // 0..5119
  const int lr = l & 15, g4 = l >> 4;
  const float NEG_INF = -__builtin_inff();

  const int b = wv / 320;
  const int u = wv - b*320;
  int r, base;
  if      (u >= 192) { r = 3; base = 192; }
  else if (u >= 96)  { r = 2; base = 96;  }
  else if (u >= 32)  { r = 1; base = 32;  }
  else               { r = 0; base = 0;   }
  const int qq = u - base;
  const int g  = r*32 + qq / (r+1);             // query group
  const int c  = qq - (qq / (r+1))*(r+1);       // chunk index
  const int t_total = (g >> 3) + 1;             // 128-key tiles this group needs
  const int t0 = c*4;
  const int t1 = min(t0 + 4, t_total);

  const bf16_t* qb = q  + (size_t)b*TT*32;
  const bf16_t* kb = kd + (size_t)b*TT*32;
  const bf16_t* vb = vT + (size_t)b*32*TT;
  const int q0 = g*16;
  const int qg = q0 + lr;                       // this lane's query row

  const bf16x8 qa = *(const bf16x8*)(qb + (size_t)(q0 + lr)*32 + g4*8);
  const bf16_t* v0r = vb + (size_t)lr*TT;
  const bf16_t* v1r = vb + (size_t)(16 + lr)*TT;

  f32x4 acc0 = {0.f,0.f,0.f,0.f}, acc1 = {0.f,0.f,0.f,0.f};
  float mrun = NEG_INF, lsum = 0.f;
  char* pb = (char*)&P[w][0];
  const int swz = (lr & 7) << 4;
  const f32x4 zf = {0.f,0.f,0.f,0.f};

  for (int t = t0; t < t1; ++t) {
    const int k0 = t * 128;
    f32x4 s[8];
    #pragma unroll
    for (int cc = 0; cc < 8; ++cc) {
      const bf16x8 kf = *(const bf16x8*)(kb + (size_t)(k0 + cc*16 + lr)*32 + g4*8);
      s[cc] = mfma16(kf, qa, zf);               // D[key][query]; lane: key=cc*16+g4*4+r, q=lr
    }
    if (t == t_total - 1) {                     // diagonal tile: mask key > query
      #pragma unroll
      for (int cc = 0; cc < 8; ++cc)
        #pragma unroll
        for (int rr = 0; rr < 4; ++rr)
          if (k0 + cc*16 + g4*4 + rr > qg) s[cc][rr] = NEG_INF;
    }
    // in-lane softmax over 32 keys + cross-group combine (2 shfl)
    float mt = NEG_INF;
    #pragma unroll
    for (int cc = 0; cc < 8; ++cc) {
      float a01 = fmaxf(s[cc][0], s[cc][1]), a23 = fmaxf(s[cc][2], s[cc][3]);
      mt = fmaxf(mt, fmaxf(a01, a23));
    }
    mt = fmaxf(mt, __shfl_xor(mt, 16));
    mt = fmaxf(mt, __shfl_xor(mt, 32));
    const float mn = fmaxf(mrun, mt);
    const float sc = __expf(mrun - mn);         // first tile: exp(-inf)=0
    float ps = 0.f;
    #pragma unroll
    for (int cc = 0; cc < 8; ++cc) {
      float p0 = __expf(s[cc][0]-mn), p1 = __expf(s[cc][1]-mn);
      float p2 = __expf(s[cc][2]-mn), p3 = __expf(s[cc][3]-mn);
      s[cc][0]=p0; s[cc][1]=p1; s[cc][2]=p2; s[cc][3]=p3;
      ps += (p0+p1) + (p2+p3);
    }
    ps += __shfl_xor(ps, 16);
    ps += __shfl_xor(ps, 32);
    lsum = lsum*sc + ps;
    mrun = mn;
    acc0 *= sc; acc1 *= sc;
    // P -> LDS: lane writes its 32 keys for query lr as 8 x b64
    #pragma unroll
    for (int cc = 0; cc < 8; ++cc) {
      bf16x4 pk;
      pk[0]=(bf16_t)s[cc][0]; pk[1]=(bf16_t)s[cc][1];
      pk[2]=(bf16_t)s[cc][2]; pk[3]=(bf16_t)s[cc][3];
      *(bf16x4*)(pb + lr*256 + ((cc*32 + g4*8) ^ swz)) = pk;
    }
    // PV: A = vT rows (d), B = P rows (q); acc[d=g4*4+r][q=lr]
    #pragma unroll
    for (int h = 0; h < 4; ++h) {
      const bf16x8 pbf = *(const bf16x8*)(pb + lr*256 + ((h*64 + g4*16) ^ swz));
      acc0 = mfma16(*(const bf16x8*)(v0r + k0 + h*32 + g4*8), pbf, acc0);
      acc1 = mfma16(*(const bf16x8*)(v1r + k0 + h*32 + g4*8), pbf, acc1);
    }
  }
  // store partial (register layout; combine reads the same layout)
  float* pa = part_acc + (size_t)wv*512;
  *(f32x4*)(pa + l*8)     = acc0;
  *(f32x4*)(pa + l*8 + 4) = acc1;
  if (l < 16) {
    part_ml[wv*32 + l]      = mrun;
    part_ml[wv*32 + 16 + l] = lsum;
  }
}

// ---------------------------------------------------------------------------
// ln1f: fused attnc + ln1.
// One wave per (batch, 16-query group): combine <=4 partials -> attn tile
// (wave-local LDS re-layout) -> MFMA attn @ WpT (K=32, 16 MFMAs) -> + bp + x
// -> LayerNorm -> y1b (coalesced via LDS bounce).
// LDS: wp_s 16K @0 | att_s 4x1K @16K | bp_s 1K @20K | y_s 4x8K @24K = 56K
// ---------------------------------------------------------------------------
__launch_bounds__(256)
__global__ void ln1f_kernel(const float* __restrict__ part_acc,
                            const float* __restrict__ part_ml,
                            const bf16_t* __restrict__ wpT,
                            const float* __restrict__ bp, const float* __restrict__ x,
                            const float* __restrict__ g1, const float* __restrict__ be1,
                            bf16_t* __restrict__ y1b)
{
  __shared__ char SM[57344];                    // wp 16K | att 4K | bp 1K | pad | y 32K
  char* wp_s  = SM;
  char* att_s = SM + 16384;
  float* bp_s = (float*)(SM + 20480);
  char* y_s   = SM + 24576;
  const int tid = threadIdx.x;
  const int w = tid >> 6, l = tid & 63;
  const int lr = l & 15, g4 = l >> 4;
  const float NEG_INF = -__builtin_inff();

  // stage WpT [256 n][32 k] -> 64B rows, chunk-XOR swizzle (pre-swizzled src)
  #pragma unroll
  for (int p = 0; p < 4; ++p) {
    const int idx = p*256 + tid;
    const int n = idx >> 2, c = idx & 3;
    gload_lds16(wpT + (size_t)n*32 + ((c ^ (n & 3)) * 8), wp_s + idx*16);
  }
  if (tid < 64) ((float4*)bp_s)[tid] = ((const float4*)bp)[tid];

  // ---- combine partials (attnc logic, per-wave); static indexing only
  const int id = blockIdx.x*4 + w;              // 0..2047
  const int b = id >> 7, g = id & 127;
  {
    const int rr = g >> 5;
    const int base = (rr == 0) ? 0 : (rr == 1) ? 32 : (rr == 2) ? 96 : 192;
    const int p0 = b*320 + base + (g - (rr << 5))*(rr + 1);
    const int nc = rr + 1;
    float M = NEG_INF;
    float mv0=NEG_INF, mv1=NEG_INF, mv2=NEG_INF, mv3=NEG_INF;
    float lv0=0, lv1=0, lv2=0, lv3=0;
    f32x4 a00={0,0,0,0}, a01={0,0,0,0}, a10={0,0,0,0}, a11={0,0,0,0};
    f32x4 a20={0,0,0,0}, a21={0,0,0,0}, a30={0,0,0,0}, a31={0,0,0,0};
    {
      const float* pa = part_acc + (size_t)p0*512;
      a00 = *(const f32x4*)(pa + l*8); a01 = *(const f32x4*)(pa + l*8 + 4);
      mv0 = part_ml[p0*32 + lr]; lv0 = part_ml[p0*32 + 16 + lr];
    }
    if (nc > 1) {
      const float* pa = part_acc + (size_t)(p0+1)*512;
      a10 = *(const f32x4*)(pa + l*8); a11 = *(const f32x4*)(pa + l*8 + 4);
      mv1 = part_ml[(p0+1)*32 + lr]; lv1 = part_ml[(p0+1)*32 + 16 + lr];
    }
    if (nc > 2) {
      const float* pa = part_acc + (size_t)(p0+2)*512;
      a20 = *(const f32x4*)(pa + l*8); a21 = *(const f32x4*)(pa + l*8 + 4);
      mv2 = part_ml[(p0+2)*32 + lr]; lv2 = part_ml[(p0+2)*32 + 16 + lr];
    }
    if (nc > 3) {
      const float* pa = part_acc + (size_t)(p0+3)*512;
      a30 = *(const f32x4*)(pa + l*8); a31 = *(const f32x4*)(pa + l*8 + 4);
      mv3 = part_ml[(p0+3)*32 + lr]; lv3 = part_ml[(p0+3)*32 + 16 + lr];
    }
    M = fmaxf(fmaxf(mv0, mv1), fmaxf(mv2, mv3));
    const float w0 = __expf(mv0 - M), w1 = __expf(mv1 - M);
    const float w2 = __expf(mv2 - M), w3 = __expf(mv3 - M);
    const float L = lv0*w0 + lv1*w1 + lv2*w2 + lv3*w3;
    const float inv = 1.0f / L;
    const f32x4 o0 = (a00*w0 + a10*w1 + a20*w2 + a30*w3) * inv;
    const f32x4 o1 = (a01*w0 + a11*w1 + a21*w2 + a31*w3) * inv;
    // att tile -> wave-local LDS: row = lr (query), feature cols swizzled
    char* ab = att_s + w*1024;
    bf16x4 h0, h1;
    #pragma unroll
    for (int r = 0; r < 4; ++r) { h0[r] = (bf16_t)o0[r]; h1[r] = (bf16_t)o1[r]; }
    *(bf16x4*)(ab + lr*64 + ((g4*8)      ^ ((lr & 3) << 4))) = h0;
    *(bf16x4*)(ab + lr*64 + ((32 + g4*8) ^ ((lr & 3) << 4))) = h1;
  }
  __syncthreads();                              // wp_s + att_s staged

  // ---- MFMA: mh[16 rows][256 cols] = att @ WpT^T
  const char* ab = att_s + w*1024;
  const bf16x8 af = *(const bf16x8*)(ab + lr*64 + ((g4*16) ^ ((lr & 3) << 4)));
  f32x4 acc[16];
  #pragma unroll
  for (int j = 0; j < 16; ++j) {
    const int n = j*16 + lr;
    const bf16x8 bf = *(const bf16x8*)(wp_s + n*64 + ((g4*16) ^ ((n & 3) << 4)));
    acc[j] = mfma16(af, bf, f32x4{0,0,0,0});
  }

  // ---- + bp + x residual, LN stats
  const int row0 = b*TT + g*16;                 // global token row base
  float bb[16];
  #pragma unroll
  for (int j = 0; j < 16; ++j) bb[j] = bp_s[j*16 + lr];
  float s1[4] = {0,0,0,0}, s2[4] = {0,0,0,0};
  #pragma unroll
  for (int j = 0; j < 16; ++j)
    #pragma unroll
    for (int r = 0; r < 4; ++r) {
      const float t = acc[j][r] + bb[j] +
                      x[(size_t)(row0 + g4*4 + r)*256 + j*16 + lr];
      acc[j][r] = t;
      s1[r] += t; s2[r] += t*t;
    }
  #pragma unroll
  for (int r = 0; r < 4; ++r) {
    #pragma unroll
    for (int m = 1; m < 16; m <<= 1) {
      s1[r] += __shfl_xor(s1[r], m); s2[r] += __shfl_xor(s2[r], m);
    }
  }
  // ---- LN + write to y_s (512-B rows, swizzled), then coalesced store
  char* yb = y_s + w*8192;
  #pragma unroll
  for (int r = 0; r < 4; ++r) {
    const float mean = s1[r] * (1.0f/256.0f);
    const float var  = s2[r] * (1.0f/256.0f) - mean*mean;
    const float rs   = rsqrtf(var + 1e-5f);
    const int mrow = g4*4 + r;
    #pragma unroll
    for (int j = 0; j < 16; ++j) {
      const int col = j*16 + lr;
      const float yv = (acc[j][r] - mean)*rs*g1[col] + be1[col];
      *(bf16_t*)(yb + mrow*512 + ((col*2) ^ ((mrow & 7) << 4))) = (bf16_t)yv;
    }
  }
  __syncthreads();                              // y_s complete
  {
    char* ybw = y_s + w*8192;
    #pragma unroll
    for (int p = 0; p < 8; ++p) {
      const int u = p*64 + l;                   // 512 x 16B units per wave
      const int mrow = u >> 5, c16 = u & 31;    // 32 units per 512-B row (FIXED)
      const bf16x8 v = *(const bf16x8*)(ybw + mrow*512 + ((c16*16) ^ ((mrow & 7) << 4)));
      *(bf16x8*)(y1b + (size_t)(row0 + mrow)*256 + c16*8) = v;
    }
  }
}

// ---------------------------------------------------------------------------
// mlp: fused MLP (R9 config -- best of family, 69 us).
// Grid 256 (1 block/CU), 1024 threads (16 waves). 16 n-chunks of 64.
// ---------------------------------------------------------------------------
__launch_bounds__(1024)
__global__ void mlp_kernel(const bf16_t* __restrict__ y1b, const bf16_t* __restrict__ w1t,
                           const float* __restrict__ b1, const bf16_t* __restrict__ w2t,
                           const float* __restrict__ b2, const float* __restrict__ g2,
                           const float* __restrict__ be2, float* __restrict__ out)
{
  __shared__ char SM[151552];
  const int tid = threadIdx.x;
  const int w = tid >> 6, l = tid & 63;
  const int lr = l & 15, g4 = l >> 4;
  const int m0 = blockIdx.x * 128;
  const int wm  = (w >> 1) * 16;        // wave's 16-token row block (FF1 & FF2)
  const int wn1 = (w & 1) * 32;         // FF1 h-col half within 64-chunk
  const int wn2 = (w & 1) * 128;        // FF2 out-col half

  *(float*)(SM + 147456 + tid*4) = b1[tid];
  asm volatile("s_waitcnt vmcnt(0) lgkmcnt(0)" ::: "memory");
  __builtin_amdgcn_sched_barrier(0);

  #define ST_W1(i, d)                                                         \
    { _Pragma("unroll")                                                       \
      for (int p_ = 0; p_ < 2; ++p_) {                                        \
        const int idx_ = p_*1024 + tid;                                       \
        const int r_ = idx_ >> 5, c_ = idx_ & 31;                             \
        const int sc_ = (c_ & 24) | ((c_ ^ r_) & 7);                          \
        gload_lds16(w1t + (size_t)((i)*64 + r_)*256 + sc_*8,                  \
                    SM + (d)*32768 + idx_*16);                                \
      } }
  #define ST_W2(i, d)                                                         \
    { _Pragma("unroll")                                                       \
      for (int p_ = 0; p_ < 2; ++p_) {                                        \
        const int idx_ = p_*1024 + tid;                                       \
        const int r_ = idx_ >> 3, c_ = idx_ & 7;                              \
        gload_lds16(w2t + (size_t)r_*1024 + (i)*64 + ((c_ ^ r_) & 7)*8,       \
                    SM + 65536 + (d)*32768 + idx_*16);                        \
      } }

  ST_W1(0, 0);
  bf16x8 aA[8];
  #pragma unroll
  for (int kk = 0; kk < 8; ++kk)
    aA[kk] = *(const bf16x8*)(y1b + (size_t)(m0 + wm + lr)*256 + kk*32 + g4*8);
  ST_W2(0, 0);
  ST_W1(1, 1);

  f32x4 oacc[8] = {};
  char* hb = SM + 131072;

  #pragma unroll 1
  for (int i = 0; i < 16; ++i) {
    if (i < 15) { asm volatile("s_waitcnt vmcnt(4)" ::: "memory"); }
    else        { asm volatile("s_waitcnt vmcnt(2)" ::: "memory"); }
    __builtin_amdgcn_sched_barrier(0);
    __builtin_amdgcn_s_barrier();
    const char* sw1 = SM + (i & 1)*32768;
    f32x4 ah0 = {0.f,0.f,0.f,0.f}, ah1 = {0.f,0.f,0.f,0.f};
    __builtin_amdgcn_s_setprio(1);
    #pragma unroll
    for (int kk = 0; kk < 8; ++kk) {
      const int off = kk*64 + g4*16;
      const int n0r = wn1 + lr, n1r = wn1 + 16 + lr;
      const bf16x8 bf0 = *(const bf16x8*)(sw1 + n0r*512 + (off ^ ((n0r & 7) << 4)));
      const bf16x8 bf1 = *(const bf16x8*)(sw1 + n1r*512 + (off ^ ((n1r & 7) << 4)));
      ah0 = mfma16(aA[kk], bf0, ah0);
      ah1 = mfma16(aA[kk], bf1, ah1);
    }
    __builtin_amdgcn_s_setprio(0);
    #pragma unroll
    for (int j = 0; j < 2; ++j) {
      const float bias = *(const float*)(SM + 147456 + (i*64 + wn1 + j*16 + lr)*4);
      const f32x4 av = j ? ah1 : ah0;
      const int hcol2 = (wn1 + j*16 + lr)*2;
      #pragma unroll
      for (int r = 0; r < 4; ++r) {
        const int hrow = wm + g4*4 + r;
        const float v = av[r] + bias;
        const float z = 1.5957691216057308f * v * fmaf(0.044715f, v*v, 1.0f);
        const float gg = v * __builtin_amdgcn_rcpf(1.0f + __expf(-z));
        *(bf16_t*)(hb + hrow*128 + (hcol2 ^ ((hrow & 7) << 4))) = (bf16_t)gg;
      }
    }
    asm volatile("s_waitcnt lgkmcnt(0)" ::: "memory");
    __builtin_amdgcn_sched_barrier(0);
    if (i < 15) { asm volatile("s_waitcnt vmcnt(2)" ::: "memory"); }
    else        { asm volatile("s_waitcnt vmcnt(0)" ::: "memory"); }
    __builtin_amdgcn_sched_barrier(0);
    __builtin_amdgcn_s_barrier();
    const char* sw2 = SM + 65536 + (i & 1)*32768;
    __builtin_amdgcn_s_setprio(1);
    #pragma unroll
    for (int kk2 = 0; kk2 < 2; ++kk2) {
      const int off = kk2*64 + g4*16;
      const int hr = wm + lr;
      const bf16x8 ha = *(const bf16x8*)(hb + hr*128 + (off ^ ((hr & 7) << 4)));
      #pragma unroll
      for (int j3 = 0; j3 < 8; ++j3) {
        const int n = wn2 + j3*16 + lr;
        const bf16x8 wb = *(const bf16x8*)(sw2 + n*128 + (off ^ ((n & 7) << 4)));
        oacc[j3] = mfma16(ha, wb, oacc[j3]);
      }
    }
    __builtin_amdgcn_s_setprio(0);
    if (i < 15) ST_W2(i+1, (i+1)&1);
    if (i < 14) ST_W1(i+2, i&1);
  }
  #undef ST_W1
  #undef ST_W2

  float b2r[8], g2r[8], be2r[8];
  #pragma unroll
  for (int j3 = 0; j3 < 8; ++j3) {
    const int col = wn2 + j3*16 + lr;
    b2r[j3] = b2[col]; g2r[j3] = g2[col]; be2r[j3] = be2[col];
  }
  #pragma unroll
  for (int r = 0; r < 4; ++r) {
    const int grow = m0 + wm + g4*4 + r;
    #pragma unroll
    for (int j3 = 0; j3 < 8; ++j3) {
      const int col = wn2 + j3*16 + lr;
      oacc[j3][r] += b2r[j3] + (float)y1b[(size_t)grow*256 + col];
    }
  }
  __syncthreads();
  float* red = (float*)SM;
  #pragma unroll
  for (int r = 0; r < 4; ++r) {
    float s1 = 0.f, s2 = 0.f;
    #pragma unroll
    for (int j3 = 0; j3 < 8; ++j3) { s1 += oacc[j3][r]; s2 += oacc[j3][r]*oacc[j3][r]; }
    #pragma unroll
    for (int m = 1; m < 16; m <<= 1) { s1 += __shfl_xor(s1, m); s2 += __shfl_xor(s2, m); }
    if (lr == 0) {
      const int rl = wm + g4*4 + r;
      red[rl*4 + (w & 1)*2]     = s1;
      red[rl*4 + (w & 1)*2 + 1] = s2;
    }
  }
  __syncthreads();
  #pragma unroll
  for (int r = 0; r < 4; ++r) {
    const int rl = wm + g4*4 + r;
    const float S1 = red[rl*4+0] + red[rl*4+2];
    const float S2 = red[rl*4+1] + red[rl*4+3];
    const float mean = S1 * (1.0f/256.0f);
    const float var  = S2 * (1.0f/256.0f) - mean*mean;
    const float rs   = rsqrtf(var + 1e-5f);
    #pragma unroll
    for (int j3 = 0; j3 < 8; ++j3) {
      const int col = wn2 + j3*16 + lr;
      out[(size_t)(m0 + rl)*256 + col] = (oacc[j3][r] - mean)*rs*g2r[j3] + be2r[j3];
    }
  }
}

// ---------------------------------------------------------------------------
extern "C" void kernel_launch(void* const* d_in, const int* in_sizes, int n_in,
                              void* d_out, int out_size, void* d_ws, size_t ws_size,
                              hipStream_t stream)
{
  const float* x   = (const float*)d_in[0];
  const float* Wq  = (const float*)d_in[1];
  const float* Wk  = (const float*)d_in[2];
  const float* Wv  = (const float*)d_in[3];
  const float* Wp  = (const float*)d_in[4];
  const float* bp  = (const float*)d_in[5];
  const float* W1  = (const float*)d_in[6];
  const float* b1  = (const float*)d_in[7];
  const float* W2  = (const float*)d_in[8];
  const float* b2  = (const float*)d_in[9];
  const float* g1  = (const float*)d_in[10];
  const float* be1 = (const float*)d_in[11];
  const float* g2  = (const float*)d_in[12];
  const float* be2 = (const float*)d_in[13];

  char* ws = (char*)d_ws;
  bf16_t* qd   = (bf16_t*)(ws + ((size_t)0  << 20));  // 2 MB
  bf16_t* kd   = (bf16_t*)(ws + ((size_t)2  << 20));  // 2 MB
  bf16_t* vTd  = (bf16_t*)(ws + ((size_t)4  << 20));  // 2 MB
  bf16_t* y1b  = (bf16_t*)(ws + ((size_t)8  << 20));  // 16 MB
  bf16_t* wqkv = (bf16_t*)(ws + ((size_t)24 << 20));
  bf16_t* wpT  = (bf16_t*)(ws + ((size_t)25 << 20));  // 16 KB
  bf16_t* w1t  = (bf16_t*)(ws + ((size_t)26 << 20));  // 512 KB
  bf16_t* w2t  = (bf16_t*)(ws + ((size_t)27 << 20));  // 512 KB
  float*  pml  = (float*) (ws + ((size_t)28 << 20));  // 640 KB
  float*  pacc = (float*) (ws + ((size_t)29 << 20));  // 10 MB
  float* out = (float*)d_out;

  prep_kernel<<<1024, 256, 0, stream>>>(Wq, Wk, Wv, Wp, W1, W2, wqkv, wpT, w1t, w2t);
  qkv_kernel<<<512, 256, 0, stream>>>(x, wqkv, qd, kd, vTd);
  attnp_kernel<<<1280, 256, 0, stream>>>(qd, kd, vTd, pacc, pml);
  ln1f_kernel<<<512, 256, 0, stream>>>(pacc, pml, wpT, bp, x, g1, be1, y1b);
  mlp_kernel<<<256, 1024, 0, stream>>>(y1b, w1t, b1, w2t, b2, g2, be2, out);
}